// Round 1
// baseline (1314.502 us; speedup 1.0000x reference)
//
#include <hip/hip_runtime.h>

#define N_NODES 10000
#define E_EDGES 320000
#define F_IN    256
#define F_PROJ  200

// ---------------- K1: P = x @ W_proj (bias dropped: cancels in p_i - p_j) ----
// Each block: 8 nodes, 256 threads (thread j < 200 computes column j for 8 rows).
__global__ void proj_kernel(const float* __restrict__ x,
                            const float* __restrict__ W,   // [F_IN][F_PROJ]
                            float* __restrict__ P) {       // [N][F_PROJ]
    __shared__ float xs[8][F_IN];
    int n0 = blockIdx.x * 8;
    for (int i = threadIdx.x; i < 8 * F_IN; i += 256) {
        int r = i >> 8, c = i & 255;
        xs[r][c] = x[(n0 + r) * F_IN + c];
    }
    __syncthreads();
    int j = threadIdx.x;
    if (j >= F_PROJ) return;
    float acc[8] = {0.f,0.f,0.f,0.f,0.f,0.f,0.f,0.f};
    for (int k = 0; k < F_IN; ++k) {
        float w = W[k * F_PROJ + j];
        #pragma unroll
        for (int r = 0; r < 8; ++r) acc[r] += xs[r][k] * w;
    }
    #pragma unroll
    for (int r = 0; r < 8; ++r) P[(n0 + r) * F_PROJ + j] = acc[r];
}

// ---------------- K2: per-edge alpha, exp, global sum, dst flags -------------
// One wave (64 lanes) per edge. block = 256 threads = 4 edges.
__global__ void alpha_kernel(const int* __restrict__ ei,      // [2][E]
                             const float* __restrict__ P,     // [N][F_PROJ]
                             const float* __restrict__ Watt,  // [F_PROJ]
                             const float* __restrict__ batt,  // [1]
                             float* __restrict__ expalpha,    // [E]
                             float* __restrict__ sumbuf,      // [1]
                             int* __restrict__ flags) {       // [N]
    __shared__ float bsum;
    if (threadIdx.x == 0) bsum = 0.f;
    __syncthreads();
    int wave = threadIdx.x >> 6;
    int lane = threadIdx.x & 63;
    int e = blockIdx.x * 4 + wave;
    if (e < E_EDGES) {
        int s = ei[e];
        int d = ei[E_EDGES + e];
        const float* Ps = P + s * F_PROJ;
        const float* Pd = P + d * F_PROJ;
        float acc = 0.f;
        for (int k = lane; k < F_PROJ; k += 64)
            acc += fabsf(Pd[k] - Ps[k]) * Watt[k];
        #pragma unroll
        for (int off = 32; off; off >>= 1) acc += __shfl_down(acc, off);
        if (lane == 0) {
            float alpha = fmaxf(acc + batt[0], 0.f);
            float ea = expf(alpha);        // alpha in [0, ~6]: safe, no max-sub
            expalpha[e] = ea;
            flags[d] = 1;                  // racy same-value store: fine
            atomicAdd(&bsum, ea);
        }
    }
    __syncthreads();
    if (threadIdx.x == 0) atomicAdd(sumbuf, bsum);
}

// ---------------- K3a: copy edge_attr -> edge_values (float4 grid-stride) ----
__global__ void copy_kernel(const float4* __restrict__ src,
                            float4* __restrict__ dst, long n4) {
    long i = (long)blockIdx.x * blockDim.x + threadIdx.x;
    long stride = (long)gridDim.x * blockDim.x;
    for (; i < n4; i += stride) dst[i] = src[i];
}

// ---------------- K3b: scatter normalized a into edge_values -----------------
__global__ void scatter_kernel(const int* __restrict__ ei,
                               const float* __restrict__ expalpha,
                               const float* __restrict__ sumbuf,
                               float* __restrict__ ev) {
    int e = blockIdx.x * 256 + threadIdx.x;
    if (e >= E_EDGES) return;
    float a = expalpha[e] / sumbuf[0];
    int s = ei[e];
    int d = ei[E_EDGES + e];
    ev[(long)s * N_NODES + d] = a;
    ev[(long)d * N_NODES + s] = a;
}

// ---------------- K4: agg[n] = flags[n] ? x[n] : 0 ---------------------------
__global__ void agg_kernel(const float* __restrict__ x,
                           const int* __restrict__ flags,
                           float* __restrict__ agg) {
    int i = blockIdx.x * 256 + threadIdx.x;
    if (i >= N_NODES * F_IN) return;
    agg[i] = flags[i >> 8] ? x[i] : 0.f;   // F_IN == 256
}

extern "C" void kernel_launch(void* const* d_in, const int* in_sizes, int n_in,
                              void* d_out, int out_size, void* d_ws, size_t ws_size,
                              hipStream_t stream) {
    (void)in_sizes; (void)n_in; (void)out_size; (void)ws_size;
    const float* x         = (const float*)d_in[0];
    const float* edge_attr = (const float*)d_in[1];
    const int*   ei        = (const int*)d_in[2];   // int32 per harness contract
    const float* W_proj    = (const float*)d_in[3];
    // d_in[4] = b_proj: cancels in p_i - p_j, unused
    const float* W_att     = (const float*)d_in[5];
    const float* b_att     = (const float*)d_in[6];

    float* agg = (float*)d_out;                       // [N][F_IN]
    float* ev  = (float*)d_out + (long)N_NODES * F_IN; // [N][N]

    // workspace layout
    char* ws = (char*)d_ws;
    float* P        = (float*)(ws);                       // 8,000,000 B
    float* expalpha = (float*)(ws + 8000000);             // 1,280,000 B
    float* sumbuf   = (float*)(ws + 9280000);             // 16 B (uses 4)
    int*   flags    = (int*)  (ws + 9280016);             // 40,000 B

    // zero the accumulator + flags (harness does not re-poison between replays)
    hipMemsetAsync(ws + 9280000, 0, 16 + 40000, stream);

    proj_kernel<<<N_NODES / 8, 256, 0, stream>>>(x, W_proj, P);
    alpha_kernel<<<E_EDGES / 4, 256, 0, stream>>>(ei, P, W_att, b_att,
                                                  expalpha, sumbuf, flags);
    long n4 = (long)N_NODES * N_NODES / 4;  // 25,000,000 float4
    copy_kernel<<<4096, 256, 0, stream>>>((const float4*)edge_attr, (float4*)ev, n4);
    scatter_kernel<<<(E_EDGES + 255) / 256, 256, 0, stream>>>(ei, expalpha, sumbuf, ev);
    agg_kernel<<<(N_NODES * F_IN) / 256, 256, 0, stream>>>(x, flags, agg);
}

// Round 2
// 336.278 us; speedup vs baseline: 3.9090x; 3.9090x over previous
//
#include <hip/hip_runtime.h>

#define N_NODES 10000
#define E_EDGES 320000
#define F_IN    256
#define F_PROJ  200

#define ALPHA_BLOCKS 2048
#define ALPHA_WAVES  (ALPHA_BLOCKS * 4)           // 8192 waves
#define ALPHA_CHUNK  ((E_EDGES + ALPHA_WAVES - 1) / ALPHA_WAVES)  // 40

// ---------------- K1: P = x @ W_proj (bias dropped: cancels in p_i - p_j) ----
__global__ void proj_kernel(const float* __restrict__ x,
                            const float* __restrict__ W,   // [F_IN][F_PROJ]
                            float* __restrict__ P) {       // [N][F_PROJ]
    __shared__ float xs[8][F_IN];
    int n0 = blockIdx.x * 8;
    for (int i = threadIdx.x; i < 8 * F_IN; i += 256) {
        int r = i >> 8, c = i & 255;
        xs[r][c] = x[(n0 + r) * F_IN + c];
    }
    __syncthreads();
    int j = threadIdx.x;
    if (j >= F_PROJ) return;
    float acc[8] = {0.f,0.f,0.f,0.f,0.f,0.f,0.f,0.f};
    for (int k = 0; k < F_IN; ++k) {
        float w = W[k * F_PROJ + j];
        #pragma unroll
        for (int r = 0; r < 8; ++r) acc[r] += xs[r][k] * w;
    }
    #pragma unroll
    for (int r = 0; r < 8; ++r) P[(n0 + r) * F_PROJ + j] = acc[r];
}

// ---------------- K2: per-edge alpha, exp, partial sums, dst flags -----------
// 2048 blocks x 4 waves; each wave owns a contiguous chunk of ~40 edges.
// One global atomic per BLOCK (2048 total), not per edge-wave (was 80k).
__global__ __launch_bounds__(256) void alpha_kernel(
                             const int* __restrict__ ei,      // [2][E]
                             const float* __restrict__ P,     // [N][F_PROJ]
                             const float* __restrict__ Watt,  // [F_PROJ]
                             const float* __restrict__ batt,  // [1]
                             float* __restrict__ expalpha,    // [E]
                             float* __restrict__ sumbuf,      // [1]
                             int* __restrict__ flags) {       // [N]
    __shared__ float bsum;
    if (threadIdx.x == 0) bsum = 0.f;
    __syncthreads();

    int wid  = blockIdx.x * 4 + (threadIdx.x >> 6);
    int lane = threadIdx.x & 63;

    // W_att held in registers: 50 lanes x float4 covers F_PROJ=200
    float4 w4 = make_float4(0.f, 0.f, 0.f, 0.f);
    if (lane < 50) w4 = ((const float4*)Watt)[lane];
    float bias = batt[0];

    int e0 = wid * ALPHA_CHUNK;
    int e1 = min(e0 + ALPHA_CHUNK, E_EDGES);
    float lsum = 0.f;

    for (int e = e0; e < e1; ++e) {
        int s = ei[e];
        int d = ei[E_EDGES + e];
        float4 ps = make_float4(0.f,0.f,0.f,0.f), pd = ps;
        if (lane < 50) {
            ps = ((const float4*)(P + (long)s * F_PROJ))[lane];
            pd = ((const float4*)(P + (long)d * F_PROJ))[lane];
        }
        float acc = fabsf(pd.x - ps.x) * w4.x
                  + fabsf(pd.y - ps.y) * w4.y
                  + fabsf(pd.z - ps.z) * w4.z
                  + fabsf(pd.w - ps.w) * w4.w;
        #pragma unroll
        for (int off = 32; off; off >>= 1) acc += __shfl_down(acc, off);
        if (lane == 0) {
            float alpha = fmaxf(acc + bias, 0.f);
            float ea = expf(alpha);        // alpha in [0, ~6]: no max-sub needed
            expalpha[e] = ea;
            flags[d] = 1;                  // racy same-value store: fine
            lsum += ea;
        }
    }
    if (lane == 0) atomicAdd(&bsum, lsum);
    __syncthreads();
    if (threadIdx.x == 0) atomicAdd(sumbuf, bsum);
}

// ---------------- K3a: copy edge_attr -> edge_values (float4 grid-stride) ----
__global__ void copy_kernel(const float4* __restrict__ src,
                            float4* __restrict__ dst, long n4) {
    long i = (long)blockIdx.x * blockDim.x + threadIdx.x;
    long stride = (long)gridDim.x * blockDim.x;
    for (; i < n4; i += stride) dst[i] = src[i];
}

// ---------------- K3b: scatter normalized a into edge_values -----------------
__global__ void scatter_kernel(const int* __restrict__ ei,
                               const float* __restrict__ expalpha,
                               const float* __restrict__ sumbuf,
                               float* __restrict__ ev) {
    int e = blockIdx.x * 256 + threadIdx.x;
    if (e >= E_EDGES) return;
    float a = expalpha[e] / sumbuf[0];
    int s = ei[e];
    int d = ei[E_EDGES + e];
    ev[(long)s * N_NODES + d] = a;
    ev[(long)d * N_NODES + s] = a;
}

// ---------------- K4: agg[n] = flags[n] ? x[n] : 0 ---------------------------
__global__ void agg_kernel(const float* __restrict__ x,
                           const int* __restrict__ flags,
                           float* __restrict__ agg) {
    int i = blockIdx.x * 256 + threadIdx.x;
    if (i >= N_NODES * F_IN) return;
    agg[i] = flags[i >> 8] ? x[i] : 0.f;   // F_IN == 256
}

extern "C" void kernel_launch(void* const* d_in, const int* in_sizes, int n_in,
                              void* d_out, int out_size, void* d_ws, size_t ws_size,
                              hipStream_t stream) {
    (void)in_sizes; (void)n_in; (void)out_size; (void)ws_size;
    const float* x         = (const float*)d_in[0];
    const float* edge_attr = (const float*)d_in[1];
    const int*   ei        = (const int*)d_in[2];   // int32 per harness contract
    const float* W_proj    = (const float*)d_in[3];
    // d_in[4] = b_proj: cancels in p_i - p_j, unused
    const float* W_att     = (const float*)d_in[5];
    const float* b_att     = (const float*)d_in[6];

    float* agg = (float*)d_out;                        // [N][F_IN]
    float* ev  = (float*)d_out + (long)N_NODES * F_IN; // [N][N]

    // workspace layout
    char* ws = (char*)d_ws;
    float* P        = (float*)(ws);                       // 8,000,000 B
    float* expalpha = (float*)(ws + 8000000);             // 1,280,000 B
    float* sumbuf   = (float*)(ws + 9280000);             // 16 B (uses 4)
    int*   flags    = (int*)  (ws + 9280016);             // 40,000 B

    // zero accumulator + flags each call (deterministic across graph replays)
    hipMemsetAsync(ws + 9280000, 0, 16 + 40000, stream);

    proj_kernel<<<N_NODES / 8, 256, 0, stream>>>(x, W_proj, P);
    alpha_kernel<<<ALPHA_BLOCKS, 256, 0, stream>>>(ei, P, W_att, b_att,
                                                   expalpha, sumbuf, flags);
    long n4 = (long)N_NODES * N_NODES / 4;  // 25,000,000 float4
    copy_kernel<<<4096, 256, 0, stream>>>((const float4*)edge_attr, (float4*)ev, n4);
    scatter_kernel<<<(E_EDGES + 255) / 256, 256, 0, stream>>>(ei, expalpha, sumbuf, ev);
    agg_kernel<<<(N_NODES * F_IN) / 256, 256, 0, stream>>>(x, flags, agg);
}

// Round 3
// 290.011 us; speedup vs baseline: 4.5326x; 1.1595x over previous
//
#include <hip/hip_runtime.h>

#define N_NODES 10000
#define E_EDGES 320000
#define F_IN    256
#define F_PROJ  200

#define ALPHA_BLOCKS 2048
#define COPY_BLOCKS  4096
#define FUSED_BLOCKS (ALPHA_BLOCKS + COPY_BLOCKS)     // 6144, role = bid % 3
#define ALPHA_WAVES  (ALPHA_BLOCKS * 4)               // 8192 waves
#define ALPHA_CHUNK  ((E_EDGES + ALPHA_WAVES - 1) / ALPHA_WAVES)  // 40

// round-to-nearest-even f32 -> bf16 bits
__device__ __forceinline__ unsigned short f32_to_bf16(float f) {
    unsigned int u = __float_as_uint(f);
    u += 0x7FFFu + ((u >> 16) & 1u);
    return (unsigned short)(u >> 16);
}
__device__ __forceinline__ float bf16_to_f32(unsigned short b) {
    return __uint_as_float(((unsigned int)b) << 16);
}

// ---------------- K1: P = x @ W_proj (bias cancels), bf16 out; also zeros ----
__global__ void proj_kernel(const float* __restrict__ x,
                            const float* __restrict__ W,    // [F_IN][F_PROJ]
                            unsigned short* __restrict__ P, // [N][F_PROJ] bf16
                            int* __restrict__ flags,        // [N] -> 0
                            float* __restrict__ sumbuf) {   // [1] -> 0
    // fold the memset: 1250 blocks x 256 threads = 320k threads >= N+1
    int gt = blockIdx.x * 256 + threadIdx.x;
    if (gt < N_NODES) flags[gt] = 0;
    if (gt == N_NODES) *sumbuf = 0.f;

    __shared__ float xs[8][F_IN];
    int n0 = blockIdx.x * 8;
    for (int i = threadIdx.x; i < 8 * F_IN; i += 256) {
        int r = i >> 8, c = i & 255;
        xs[r][c] = x[(n0 + r) * F_IN + c];
    }
    __syncthreads();
    int j = threadIdx.x;
    if (j >= F_PROJ) return;
    float acc[8] = {0.f,0.f,0.f,0.f,0.f,0.f,0.f,0.f};
    for (int k = 0; k < F_IN; ++k) {
        float w = W[k * F_PROJ + j];
        #pragma unroll
        for (int r = 0; r < 8; ++r) acc[r] += xs[r][k] * w;
    }
    #pragma unroll
    for (int r = 0; r < 8; ++r) P[(long)(n0 + r) * F_PROJ + j] = f32_to_bf16(acc[r]);
}

// ---------------- K2: fused  (1/3 blocks: per-edge alpha)  (2/3: big copy) ---
__global__ __launch_bounds__(256) void alpha_copy_kernel(
                             const int* __restrict__ ei,        // [2][E]
                             const unsigned short* __restrict__ P, // [N][200] bf16
                             const float* __restrict__ Watt,    // [F_PROJ]
                             const float* __restrict__ batt,    // [1]
                             float* __restrict__ expalpha,      // [E]
                             float* __restrict__ sumbuf,        // [1]
                             int* __restrict__ flags,           // [N]
                             const float4* __restrict__ csrc,   // edge_attr
                             float4* __restrict__ cdst,         // edge_values
                             long n4) {
    int role = blockIdx.x % 3;
    if (role != 0) {
        // ---- copy role: 4096 virtual copy blocks, grid-stride float4 ----
        long cid = (long)(blockIdx.x / 3) * 2 + (role - 1);   // 0..4095
        long i = cid * 256 + threadIdx.x;
        const long stride = (long)COPY_BLOCKS * 256;
        for (; i < n4; i += stride) cdst[i] = csrc[i];
        return;
    }
    // ---- alpha role: 2048 virtual blocks x 4 waves, ~40 edges per wave ----
    __shared__ float bsum;
    if (threadIdx.x == 0) bsum = 0.f;
    __syncthreads();

    int aid  = blockIdx.x / 3;                     // 0..2047
    int wid  = aid * 4 + (threadIdx.x >> 6);
    int lane = threadIdx.x & 63;

    // per-lane slice: lane < 50 owns elements [lane*4, lane*4+4)
    float4 w4 = make_float4(0.f, 0.f, 0.f, 0.f);
    if (lane < 50) w4 = ((const float4*)Watt)[lane];
    float bias = batt[0];

    int e0 = wid * ALPHA_CHUNK;
    int e1 = min(e0 + ALPHA_CHUNK, E_EDGES);
    float lsum = 0.f;

    for (int e = e0; e < e1; ++e) {
        int s = ei[e];
        int d = ei[E_EDGES + e];
        float acc = 0.f;
        if (lane < 50) {
            // 8B per lane: 4 bf16 values of each row
            uint2 us = *(const uint2*)(P + (long)s * F_PROJ + lane * 4);
            uint2 ud = *(const uint2*)(P + (long)d * F_PROJ + lane * 4);
            float s0 = bf16_to_f32((unsigned short)(us.x & 0xFFFF));
            float s1 = bf16_to_f32((unsigned short)(us.x >> 16));
            float s2 = bf16_to_f32((unsigned short)(us.y & 0xFFFF));
            float s3 = bf16_to_f32((unsigned short)(us.y >> 16));
            float d0 = bf16_to_f32((unsigned short)(ud.x & 0xFFFF));
            float d1 = bf16_to_f32((unsigned short)(ud.x >> 16));
            float d2 = bf16_to_f32((unsigned short)(ud.y & 0xFFFF));
            float d3 = bf16_to_f32((unsigned short)(ud.y >> 16));
            acc = fabsf(d0 - s0) * w4.x + fabsf(d1 - s1) * w4.y
                + fabsf(d2 - s2) * w4.z + fabsf(d3 - s3) * w4.w;
        }
        #pragma unroll
        for (int off = 32; off; off >>= 1) acc += __shfl_down(acc, off);
        if (lane == 0) {
            float alpha = fmaxf(acc + bias, 0.f);
            float ea = expf(alpha);        // alpha in [0,~6]: no max-sub needed
            expalpha[e] = ea;
            flags[d] = 1;                  // racy same-value store: fine
            lsum += ea;
        }
    }
    if (lane == 0) atomicAdd(&bsum, lsum);
    __syncthreads();
    if (threadIdx.x == 0) atomicAdd(sumbuf, bsum);
}

// ---------------- K3: fused  (blocks<2500: agg float4)  (rest: scatter) -----
__global__ void scatter_agg_kernel(const int* __restrict__ ei,
                                   const float* __restrict__ expalpha,
                                   const float* __restrict__ sumbuf,
                                   float* __restrict__ ev,
                                   const float4* __restrict__ x4,
                                   const int* __restrict__ flags,
                                   float4* __restrict__ agg4) {
    int b = blockIdx.x;
    if (b < 2500) {
        // agg: N*F_IN/4 = 640000 float4; flag index = (i4*4)>>8 = i4>>6
        int i4 = b * 256 + threadIdx.x;
        float4 v = x4[i4];
        if (!flags[i4 >> 6]) v = make_float4(0.f, 0.f, 0.f, 0.f);
        agg4[i4] = v;
    } else {
        int e = (b - 2500) * 256 + threadIdx.x;
        if (e >= E_EDGES) return;
        float a = expalpha[e] / sumbuf[0];
        int s = ei[e];
        int d = ei[E_EDGES + e];
        ev[(long)s * N_NODES + d] = a;
        ev[(long)d * N_NODES + s] = a;
    }
}

extern "C" void kernel_launch(void* const* d_in, const int* in_sizes, int n_in,
                              void* d_out, int out_size, void* d_ws, size_t ws_size,
                              hipStream_t stream) {
    (void)in_sizes; (void)n_in; (void)out_size; (void)ws_size;
    const float* x         = (const float*)d_in[0];
    const float* edge_attr = (const float*)d_in[1];
    const int*   ei        = (const int*)d_in[2];   // int32 per harness contract
    const float* W_proj    = (const float*)d_in[3];
    // d_in[4] = b_proj: cancels in p_i - p_j, unused
    const float* W_att     = (const float*)d_in[5];
    const float* b_att     = (const float*)d_in[6];

    float* agg = (float*)d_out;                        // [N][F_IN]
    float* ev  = (float*)d_out + (long)N_NODES * F_IN; // [N][N]

    // workspace layout
    char* ws = (char*)d_ws;
    unsigned short* P = (unsigned short*)(ws);            // 4,000,000 B (bf16)
    float* expalpha   = (float*)(ws + 4000000);           // 1,280,000 B
    float* sumbuf     = (float*)(ws + 5280000);           // 16 B (uses 4)
    int*   flags      = (int*)  (ws + 5280016);           // 40,000 B

    proj_kernel<<<N_NODES / 8, 256, 0, stream>>>(x, W_proj, P, flags, sumbuf);

    long n4 = (long)N_NODES * N_NODES / 4;  // 25,000,000 float4
    alpha_copy_kernel<<<FUSED_BLOCKS, 256, 0, stream>>>(
        ei, P, W_att, b_att, expalpha, sumbuf, flags,
        (const float4*)edge_attr, (float4*)ev, n4);

    scatter_agg_kernel<<<2500 + (E_EDGES + 255) / 256, 256, 0, stream>>>(
        ei, expalpha, sumbuf, ev, (const float4*)x, flags, (float4*)agg);
}

// Round 4
// 251.562 us; speedup vs baseline: 5.2254x; 1.1528x over previous
//
#include <hip/hip_runtime.h>

#define N_NODES 10000
#define E_EDGES 320000
#define F_IN    256
#define F_PROJ  200

#define ALPHA_BLOCKS 2048
#define COPY_BLOCKS  4096
#define FUSED_BLOCKS (ALPHA_BLOCKS + COPY_BLOCKS)     // 6144, role = bid % 3
#define ALPHA_WAVES  (ALPHA_BLOCKS * 4)               // 8192 waves
#define ALPHA_CHUNK  ((E_EDGES + ALPHA_WAVES - 1) / ALPHA_WAVES)  // 40

// proper vector type so __builtin_nontemporal_* accepts it (HIP float4 is a struct)
typedef float vfloat4 __attribute__((ext_vector_type(4)));

// round-to-nearest-even f32 -> bf16 bits
__device__ __forceinline__ unsigned short f32_to_bf16(float f) {
    unsigned int u = __float_as_uint(f);
    u += 0x7FFFu + ((u >> 16) & 1u);
    return (unsigned short)(u >> 16);
}
__device__ __forceinline__ float bf16_to_f32(unsigned short b) {
    return __uint_as_float(((unsigned int)b) << 16);
}

// ---------------- K1: P = x @ W_proj (bias cancels), bf16 out; also zeros ----
__global__ void proj_kernel(const float* __restrict__ x,
                            const float* __restrict__ W,    // [F_IN][F_PROJ]
                            unsigned short* __restrict__ P, // [N][F_PROJ] bf16
                            int* __restrict__ flags,        // [N] -> 0
                            float* __restrict__ sumbuf) {   // [1] -> 0
    // fold the memset: 1250 blocks x 256 threads = 320k threads >= N+1
    int gt = blockIdx.x * 256 + threadIdx.x;
    if (gt < N_NODES) flags[gt] = 0;
    if (gt == N_NODES) *sumbuf = 0.f;

    __shared__ float xs[8][F_IN];
    int n0 = blockIdx.x * 8;
    for (int i = threadIdx.x; i < 8 * F_IN; i += 256) {
        int r = i >> 8, c = i & 255;
        xs[r][c] = x[(n0 + r) * F_IN + c];
    }
    __syncthreads();
    int j = threadIdx.x;
    if (j >= F_PROJ) return;
    float acc[8] = {0.f,0.f,0.f,0.f,0.f,0.f,0.f,0.f};
    for (int k = 0; k < F_IN; ++k) {
        float w = W[k * F_PROJ + j];
        #pragma unroll
        for (int r = 0; r < 8; ++r) acc[r] += xs[r][k] * w;
    }
    #pragma unroll
    for (int r = 0; r < 8; ++r) P[(long)(n0 + r) * F_PROJ + j] = f32_to_bf16(acc[r]);
}

// ---------------- K2: fused  (1/3 blocks: per-edge alpha)  (2/3: nt copy) ----
// Copy uses non-temporal load/store (nt bit): the 800 MB stream must NOT
// evict P (4 MB) from L2/LLC, or alpha's row gathers fall to HBM and the
// random+stream interleave halves DRAM efficiency (round-3 lesson:
// 3.0 TB/s, FETCH showed ~280 MB of gather misses).
__global__ __launch_bounds__(256) void alpha_copy_kernel(
                             const int* __restrict__ ei,        // [2][E]
                             const unsigned short* __restrict__ P, // [N][200] bf16
                             const float* __restrict__ Watt,    // [F_PROJ]
                             const float* __restrict__ batt,    // [1]
                             float* __restrict__ expalpha,      // [E]
                             float* __restrict__ sumbuf,        // [1]
                             int* __restrict__ flags,           // [N]
                             const vfloat4* __restrict__ csrc,  // edge_attr
                             vfloat4* __restrict__ cdst,        // edge_values
                             long n4) {
    int role = blockIdx.x % 3;
    if (role != 0) {
        // ---- copy role: 4096 virtual copy blocks, grid-stride, nt, x2 unroll
        long cid = (long)(blockIdx.x / 3) * 2 + (role - 1);   // 0..4095
        long i = cid * 256 + threadIdx.x;
        const long stride = (long)COPY_BLOCKS * 256;
        while (i + stride < n4) {
            vfloat4 v0 = __builtin_nontemporal_load(csrc + i);
            vfloat4 v1 = __builtin_nontemporal_load(csrc + i + stride);
            __builtin_nontemporal_store(v0, cdst + i);
            __builtin_nontemporal_store(v1, cdst + i + stride);
            i += 2 * stride;
        }
        if (i < n4) {
            vfloat4 v = __builtin_nontemporal_load(csrc + i);
            __builtin_nontemporal_store(v, cdst + i);
        }
        return;
    }
    // ---- alpha role: 2048 virtual blocks x 4 waves, ~40 edges per wave ----
    __shared__ float bsum;
    if (threadIdx.x == 0) bsum = 0.f;
    __syncthreads();

    int aid  = blockIdx.x / 3;                     // 0..2047
    int wid  = aid * 4 + (threadIdx.x >> 6);
    int lane = threadIdx.x & 63;

    // per-lane slice: lane < 50 owns elements [lane*4, lane*4+4)
    float4 w4 = make_float4(0.f, 0.f, 0.f, 0.f);
    if (lane < 50) w4 = ((const float4*)Watt)[lane];
    float bias = batt[0];

    int e0 = wid * ALPHA_CHUNK;
    int e1 = min(e0 + ALPHA_CHUNK, E_EDGES);
    float lsum = 0.f;

    for (int e = e0; e < e1; ++e) {
        int s = ei[e];
        int d = ei[E_EDGES + e];
        float acc = 0.f;
        if (lane < 50) {
            // 8B per lane: 4 bf16 values of each row (rows L2/LLC-resident now)
            uint2 us = *(const uint2*)(P + (long)s * F_PROJ + lane * 4);
            uint2 ud = *(const uint2*)(P + (long)d * F_PROJ + lane * 4);
            float s0 = bf16_to_f32((unsigned short)(us.x & 0xFFFF));
            float s1 = bf16_to_f32((unsigned short)(us.x >> 16));
            float s2 = bf16_to_f32((unsigned short)(us.y & 0xFFFF));
            float s3 = bf16_to_f32((unsigned short)(us.y >> 16));
            float d0 = bf16_to_f32((unsigned short)(ud.x & 0xFFFF));
            float d1 = bf16_to_f32((unsigned short)(ud.x >> 16));
            float d2 = bf16_to_f32((unsigned short)(ud.y & 0xFFFF));
            float d3 = bf16_to_f32((unsigned short)(ud.y >> 16));
            acc = fabsf(d0 - s0) * w4.x + fabsf(d1 - s1) * w4.y
                + fabsf(d2 - s2) * w4.z + fabsf(d3 - s3) * w4.w;
        }
        #pragma unroll
        for (int off = 32; off; off >>= 1) acc += __shfl_down(acc, off);
        if (lane == 0) {
            float alpha = fmaxf(acc + bias, 0.f);
            float ea = expf(alpha);        // alpha in [0,~6]: no max-sub needed
            expalpha[e] = ea;
            flags[d] = 1;                  // racy same-value store: fine
            lsum += ea;
        }
    }
    if (lane == 0) atomicAdd(&bsum, lsum);
    __syncthreads();
    if (threadIdx.x == 0) atomicAdd(sumbuf, bsum);
}

// ---------------- K3: fused  (blocks<2500: agg float4)  (rest: scatter) -----
__global__ void scatter_agg_kernel(const int* __restrict__ ei,
                                   const float* __restrict__ expalpha,
                                   const float* __restrict__ sumbuf,
                                   float* __restrict__ ev,
                                   const float4* __restrict__ x4,
                                   const int* __restrict__ flags,
                                   float4* __restrict__ agg4) {
    int b = blockIdx.x;
    if (b < 2500) {
        // agg: N*F_IN/4 = 640000 float4; flag index = (i4*4)>>8 = i4>>6
        int i4 = b * 256 + threadIdx.x;
        float4 v = x4[i4];
        if (!flags[i4 >> 6]) v = make_float4(0.f, 0.f, 0.f, 0.f);
        agg4[i4] = v;
    } else {
        int e = (b - 2500) * 256 + threadIdx.x;
        if (e >= E_EDGES) return;
        float a = expalpha[e] / sumbuf[0];
        int s = ei[e];
        int d = ei[E_EDGES + e];
        ev[(long)s * N_NODES + d] = a;
        ev[(long)d * N_NODES + s] = a;
    }
}

extern "C" void kernel_launch(void* const* d_in, const int* in_sizes, int n_in,
                              void* d_out, int out_size, void* d_ws, size_t ws_size,
                              hipStream_t stream) {
    (void)in_sizes; (void)n_in; (void)out_size; (void)ws_size;
    const float* x         = (const float*)d_in[0];
    const float* edge_attr = (const float*)d_in[1];
    const int*   ei        = (const int*)d_in[2];   // int32 per harness contract
    const float* W_proj    = (const float*)d_in[3];
    // d_in[4] = b_proj: cancels in p_i - p_j, unused
    const float* W_att     = (const float*)d_in[5];
    const float* b_att     = (const float*)d_in[6];

    float* agg = (float*)d_out;                        // [N][F_IN]
    float* ev  = (float*)d_out + (long)N_NODES * F_IN; // [N][N]

    // workspace layout
    char* ws = (char*)d_ws;
    unsigned short* P = (unsigned short*)(ws);            // 4,000,000 B (bf16)
    float* expalpha   = (float*)(ws + 4000000);           // 1,280,000 B
    float* sumbuf     = (float*)(ws + 5280000);           // 16 B (uses 4)
    int*   flags      = (int*)  (ws + 5280016);           // 40,000 B

    proj_kernel<<<N_NODES / 8, 256, 0, stream>>>(x, W_proj, P, flags, sumbuf);

    long n4 = (long)N_NODES * N_NODES / 4;  // 25,000,000 float4
    alpha_copy_kernel<<<FUSED_BLOCKS, 256, 0, stream>>>(
        ei, P, W_att, b_att, expalpha, sumbuf, flags,
        (const vfloat4*)edge_attr, (vfloat4*)ev, n4);

    scatter_agg_kernel<<<2500 + (E_EDGES + 255) / 256, 256, 0, stream>>>(
        ei, expalpha, sumbuf, ev, (const float4*)x, flags, (float4*)agg);
}

// Round 5
// 249.337 us; speedup vs baseline: 5.2720x; 1.0089x over previous
//
#include <hip/hip_runtime.h>

#define N_NODES 10000
#define E_EDGES 320000
#define F_IN    256
#define F_PROJ  200

#define N4_TOTAL 25000000L          // ev / edge_attr in float4s
#define S1_SPLIT 4000000L           // float4s copied by K1 (128 MB traffic)

#define K1_PROJ_BLOCKS 1250
#define K1_COPY_BLOCKS 768
#define K1_BLOCKS (K1_PROJ_BLOCKS + K1_COPY_BLOCKS)

#define K2_BLOCKS 6144              // role = bid & 3; 0 -> alpha+agg, 1..3 -> copy
#define K2_ALPHA_BLOCKS 1536
#define K2_COPY_BLOCKS (K2_BLOCKS - K2_ALPHA_BLOCKS)          // 4608
#define K2_ALPHA_WAVES (K2_ALPHA_BLOCKS * 4)                  // 6144
#define ALPHA_CHUNK ((E_EDGES + K2_ALPHA_WAVES - 1) / K2_ALPHA_WAVES)  // 53
#define AGG_N4 (N_NODES * F_IN / 4)                           // 640000
#define AGG_CHUNK ((AGG_N4 + K2_ALPHA_BLOCKS - 1) / K2_ALPHA_BLOCKS)  // 417

typedef float vfloat4 __attribute__((ext_vector_type(4)));

__device__ __forceinline__ unsigned short f32_to_bf16(float f) {
    unsigned int u = __float_as_uint(f);
    u += 0x7FFFu + ((u >> 16) & 1u);
    return (unsigned short)(u >> 16);
}
__device__ __forceinline__ float bf16_to_f32(unsigned short b) {
    return __uint_as_float(((unsigned int)b) << 16);
}

// ---------------- K1: proj + flag-scan (deps-only) ∥ copy [0, S1) ------------
// flags depends only on edge_index, so it's computed here, freeing agg to
// overlap the big copy in K2.
__global__ __launch_bounds__(256) void k1_proj_flags_copy(
        const float* __restrict__ x,
        const float* __restrict__ W,          // [F_IN][F_PROJ]
        unsigned short* __restrict__ P,       // [N][F_PROJ] bf16
        const int* __restrict__ ei,           // [2][E]
        int* __restrict__ flags,              // [N], pre-zeroed by memset
        const vfloat4* __restrict__ csrc,
        vfloat4* __restrict__ cdst) {
    int bid = blockIdx.x, tid = threadIdx.x;
    if (bid >= K1_PROJ_BLOCKS) {
        // ---- copy role: [0, S1), nt both ways, 2x unroll ----
        long i = (long)(bid - K1_PROJ_BLOCKS) * 256 + tid;
        const long stride = (long)K1_COPY_BLOCKS * 256;
        while (i + stride < S1_SPLIT) {
            vfloat4 v0 = __builtin_nontemporal_load(csrc + i);
            vfloat4 v1 = __builtin_nontemporal_load(csrc + i + stride);
            __builtin_nontemporal_store(v0, cdst + i);
            __builtin_nontemporal_store(v1, cdst + i + stride);
            i += 2 * stride;
        }
        if (i < S1_SPLIT) {
            vfloat4 v = __builtin_nontemporal_load(csrc + i);
            __builtin_nontemporal_store(v, cdst + i);
        }
        return;
    }
    // ---- flag scan: 1250*256 = 320000 threads cover E exactly ----
    int gt = bid * 256 + tid;
    flags[ei[E_EDGES + gt]] = 1;        // racy same-value store: fine

    // ---- proj: 8 nodes per block ----
    __shared__ float xs[8][F_IN];
    int n0 = bid * 8;
    for (int i = tid; i < 8 * F_IN / 4; i += 256)
        ((float4*)xs)[i] = ((const float4*)(x + (long)n0 * F_IN))[i];
    __syncthreads();
    int j = tid;
    if (j >= F_PROJ) return;
    float acc[8] = {0.f,0.f,0.f,0.f,0.f,0.f,0.f,0.f};
    for (int k = 0; k < F_IN; ++k) {
        float w = W[k * F_PROJ + j];
        #pragma unroll
        for (int r = 0; r < 8; ++r) acc[r] += xs[r][k] * w;
    }
    #pragma unroll
    for (int r = 0; r < 8; ++r) P[(long)(n0 + r) * F_PROJ + j] = f32_to_bf16(acc[r]);
}

// ---------------- K2: (1/4: alpha then agg) ∥ (3/4: copy [S1, N4)) -----------
__global__ __launch_bounds__(256) void k2_alpha_agg_copy(
        const int* __restrict__ ei,
        const unsigned short* __restrict__ P,
        const float* __restrict__ Watt,
        const float* __restrict__ batt,
        float* __restrict__ expalpha,
        float* __restrict__ sumbuf,           // pre-zeroed
        const int* __restrict__ flags,        // from K1
        const float4* __restrict__ x4,
        float4* __restrict__ agg4,
        const vfloat4* __restrict__ csrc,
        vfloat4* __restrict__ cdst) {
    int bid = blockIdx.x, tid = threadIdx.x;
    int role = bid & 3;
    if (role != 0) {
        long cid = (long)(bid >> 2) * 3 + (role - 1);   // 0..4607
        long i = S1_SPLIT + cid * 256 + tid;
        const long stride = (long)K2_COPY_BLOCKS * 256;
        while (i + stride < N4_TOTAL) {
            vfloat4 v0 = __builtin_nontemporal_load(csrc + i);
            vfloat4 v1 = __builtin_nontemporal_load(csrc + i + stride);
            __builtin_nontemporal_store(v0, cdst + i);
            __builtin_nontemporal_store(v1, cdst + i + stride);
            i += 2 * stride;
        }
        if (i < N4_TOTAL) {
            vfloat4 v = __builtin_nontemporal_load(csrc + i);
            __builtin_nontemporal_store(v, cdst + i);
        }
        return;
    }
    // ---- alpha role ----
    __shared__ float bsum;
    if (tid == 0) bsum = 0.f;
    __syncthreads();

    int aid  = bid >> 2;                        // 0..1535
    int wid  = aid * 4 + (tid >> 6);
    int lane = tid & 63;

    float4 w4 = make_float4(0.f, 0.f, 0.f, 0.f);
    if (lane < 50) w4 = ((const float4*)Watt)[lane];
    float bias = batt[0];

    int e0 = wid * ALPHA_CHUNK;
    int e1 = min(e0 + ALPHA_CHUNK, E_EDGES);
    float lsum = 0.f;

    for (int e = e0; e < e1; ++e) {
        int s = ei[e];
        int d = ei[E_EDGES + e];
        float acc = 0.f;
        if (lane < 50) {
            uint2 us = *(const uint2*)(P + (long)s * F_PROJ + lane * 4);
            uint2 ud = *(const uint2*)(P + (long)d * F_PROJ + lane * 4);
            acc = fabsf(bf16_to_f32((unsigned short)(ud.x & 0xFFFF)) -
                        bf16_to_f32((unsigned short)(us.x & 0xFFFF))) * w4.x
                + fabsf(bf16_to_f32((unsigned short)(ud.x >> 16)) -
                        bf16_to_f32((unsigned short)(us.x >> 16))) * w4.y
                + fabsf(bf16_to_f32((unsigned short)(ud.y & 0xFFFF)) -
                        bf16_to_f32((unsigned short)(us.y & 0xFFFF))) * w4.z
                + fabsf(bf16_to_f32((unsigned short)(ud.y >> 16)) -
                        bf16_to_f32((unsigned short)(us.y >> 16))) * w4.w;
        }
        #pragma unroll
        for (int off = 32; off; off >>= 1) acc += __shfl_down(acc, off);
        if (lane == 0) {
            float alpha = fmaxf(acc + bias, 0.f);
            float ea = expf(alpha);          // alpha in [0,~6]: safe
            expalpha[e] = ea;
            lsum += ea;
        }
    }
    if (lane == 0) atomicAdd(&bsum, lsum);
    __syncthreads();
    if (tid == 0) atomicAdd(sumbuf, bsum);

    // ---- agg (flags ready since K1): ~417 float4 per alpha block ----
    long a0 = (long)aid * AGG_CHUNK;
    long a1 = a0 + AGG_CHUNK; if (a1 > AGG_N4) a1 = AGG_N4;
    for (long i = a0 + tid; i < a1; i += 256) {
        float4 v = x4[i];
        if (!flags[i >> 6]) v = make_float4(0.f, 0.f, 0.f, 0.f);
        agg4[i] = v;
    }
}

// ---------------- K3: scatter a into ev (must follow full copy) --------------
__global__ __launch_bounds__(256) void k3_scatter(
        const int* __restrict__ ei,
        const float* __restrict__ expalpha,
        const float* __restrict__ sumbuf,
        float* __restrict__ ev) {
    int e = blockIdx.x * 256 + threadIdx.x;
    if (e >= E_EDGES) return;
    float a = expalpha[e] / sumbuf[0];
    int s = ei[e];
    int d = ei[E_EDGES + e];
    ev[(long)s * N_NODES + d] = a;
    ev[(long)d * N_NODES + s] = a;
}

extern "C" void kernel_launch(void* const* d_in, const int* in_sizes, int n_in,
                              void* d_out, int out_size, void* d_ws, size_t ws_size,
                              hipStream_t stream) {
    (void)in_sizes; (void)n_in; (void)out_size; (void)ws_size;
    const float* x         = (const float*)d_in[0];
    const float* edge_attr = (const float*)d_in[1];
    const int*   ei        = (const int*)d_in[2];
    const float* W_proj    = (const float*)d_in[3];
    // d_in[4] = b_proj: cancels in p_i - p_j, unused
    const float* W_att     = (const float*)d_in[5];
    const float* b_att     = (const float*)d_in[6];

    float* agg = (float*)d_out;                        // [N][F_IN]
    float* ev  = (float*)d_out + (long)N_NODES * F_IN; // [N][N]

    char* ws = (char*)d_ws;
    unsigned short* P = (unsigned short*)(ws);            // 4,000,000 B
    float* expalpha   = (float*)(ws + 4000000);           // 1,280,000 B
    int*   flags      = (int*)  (ws + 5280000);           // 40,000 B
    float* sumbuf     = (float*)(ws + 5320000);           // 16 B

    // zero flags + sumbuf (one small async memset; graph-capture safe)
    hipMemsetAsync(ws + 5280000, 0, 40016, stream);

    k1_proj_flags_copy<<<K1_BLOCKS, 256, 0, stream>>>(
        x, W_proj, P, ei, flags, (const vfloat4*)edge_attr, (vfloat4*)ev);

    k2_alpha_agg_copy<<<K2_BLOCKS, 256, 0, stream>>>(
        ei, P, W_att, b_att, expalpha, sumbuf, flags,
        (const float4*)x, (float4*)agg,
        (const vfloat4*)edge_attr, (vfloat4*)ev);

    k3_scatter<<<(E_EDGES + 255) / 256, 256, 0, stream>>>(ei, expalpha, sumbuf, ev);
}